// Round 12
// baseline (1087.258 us; speedup 1.0000x reference)
//
#include <hip/hip_runtime.h>

#define KS 49
#define PADL 20
#define W 512
#define HH 512
#define PW 559          // padded width; odd LDS stride -> all patterns <=2-way banked
#define NPROWS 553      // padded rows touched: p = 0..552 (8*63+48)
#define TPB 512
#define PFD 8           // V-pass prefetch depth (rotating reg buffer, static idx)

__global__ __launch_bounds__(TPB, 4)
void fd2d_vcol(const float* __restrict__ x, const float* __restrict__ filt,
               float* __restrict__ out) {
    __shared__ float ldsH[32 * PW];   // 71,552 B -> 2 blocks/CU

    const int tid = threadIdx.x;
    const int l = tid & 63;
    const int w = tid >> 6;                    // wave 0..7 owns columns [64w, 64w+64)
    const int plane = blockIdx.x;              // b*64 + c
    const float* __restrict__ xp = x + (size_t)plane * (W * HH);
    const float* __restrict__ f24 = filt + 24 * KS;  // row 24 of outer-product filter

    // separable identity: filt[i][j] = k_i k_j / S; raw row-24 taps in both passes,
    // one final inv_s^2 restores exactly k_i k_j / S.
    float s24 = 0.f;
#pragma unroll
    for (int j = 0; j < KS; ++j) s24 += f24[j];
    const float inv_s = 1.0f / s24;
    const float inv_s2 = inv_s * inv_s;

    // ---- vertical pass: this thread owns column x = 64w + l, all 64 output rows.
    // Whole block reads one contiguous 2KB row per step -> fetch ~1.0x input.
    const float* __restrict__ colp = xp + (w << 6) + l;

    float acc[64];
#pragma unroll
    for (int r = 0; r < 64; ++r) acc[r] = 0.f;

    // y(p) with reflect padding (top 20 / bottom 27, edge excluded)
#define SRCY(p_) ({ int y_ = (p_) - PADL;                         \
                    y_ = y_ < 0 ? -y_ : y_;                       \
                    y_ = y_ > (HH - 1) ? (2 * (HH - 1) - y_) : y_; y_; })

    float vbuf[PFD];
#pragma unroll
    for (int p = 0; p < PFD; ++p) vbuf[p] = colp[SRCY(p) * W];

    // One V-step. p_ must be compile-time (loops chunked so each #pragma unroll
    // stays under the full-unroll threshold; refused unroll => scratch).
#define VSTEP(p_)                                                              \
    {                                                                          \
        const float v_ = vbuf[(p_) & (PFD - 1)];                               \
        if ((p_) + PFD < NPROWS)                                               \
            vbuf[(p_) & (PFD - 1)] = colp[SRCY((p_) + PFD) * W];               \
        _Pragma("unroll")                                                      \
        for (int r_ = 0; r_ < 64; ++r_) {                                      \
            const int j_ = (p_) - (r_ << 3);                                   \
            if (j_ >= 0 && j_ < KS)          /* compile-time predicate */      \
                acc[r_] = fmaf(f24[j_], v_, acc[r_]); /* s_load weight */      \
        }                                                                      \
    }

    // ---- horizontal pass for one 32-row half (LDS reuse); coverage bijective:
    // waves {hw, hw+4} share rows (hw<<3)+(l>>3), split ox halves via hq.
    const int hq = w >> 2;
    const int hw = w & 3;
    const int oyl_c = (hw << 3) + (l >> 3);

#define HPASS(half_)                                                           \
    {                                                                          \
        __syncthreads();              /* prev half's LDS reads complete */     \
        _Pragma("unroll")                                                      \
        for (int r_ = 0; r_ < 32; ++r_) {                                      \
            const float av_ = acc[((half_) << 5) + r_];                        \
            ldsH[r_ * PW + PADL + (w << 6) + l] = av_;  /* free banks */       \
            if (w == 0 && l >= 1 && l <= 20)      /* left pad col 20-l <- x=l */\
                ldsH[r_ * PW + (PADL - l)] = av_;                              \
            if (w == 7 && l >= 36 && l <= 62)     /* right pad col 594-l <- x=448+l */\
                ldsH[r_ * PW + (594 - l)] = av_;                               \
        }                                                                      \
        __syncthreads();              /* writes visible */                     \
        const int oy_ = ((half_) << 5) + oyl_c;                                \
        float* o_ = out + ((size_t)plane << 12) + (oy_ << 6);                  \
        const float* rowp_ = &ldsH[oyl_c * PW];                                \
        _Pragma("unroll")                                                      \
        for (int i_ = 0; i_ < 4; ++i_) {                                       \
            const int ox_ = (l & 7) + ((i_ + (hq << 2)) << 3);                 \
            const float* rp_ = rowp_ + (ox_ << 3);                             \
            float s_ = 0.f;                                                    \
            _Pragma("unroll")                                                  \
            for (int k_ = 0; k_ < KS; ++k_) s_ = fmaf(f24[k_], rp_[k_], s_);   \
            o_[ox_] = s_ * inv_s2;   /* 2-way LDS banks: (15*row+8*ox+k)%32 */ \
        }                                                                      \
    }

    // V-stream with half-0 H-pass overlapped: acc[0..31] complete after p=296
    // (needs p up to 8*31+48), so run H half 0 there; remaining 256 V-rows'
    // HBM latency hides the LDS phase.
#pragma unroll
    for (int p = 0; p < 140; ++p) VSTEP(p)
#pragma unroll
    for (int p = 140; p < 297; ++p) VSTEP(p)

    HPASS(0)

#pragma unroll
    for (int p = 297; p < 420; ++p) VSTEP(p)
#pragma unroll
    for (int p = 420; p < NPROWS; ++p) VSTEP(p)

    HPASS(1)
}

extern "C" void kernel_launch(void* const* d_in, const int* in_sizes, int n_in,
                              void* d_out, int out_size, void* d_ws, size_t ws_size,
                              hipStream_t stream) {
    const float* x    = (const float*)d_in[0];
    const float* filt = (const float*)d_in[1];
    float* out        = (float*)d_out;
    const int planes = in_sizes[0] / (W * HH);   // 8*64 = 512
    fd2d_vcol<<<dim3(planes), dim3(TPB), 0, stream>>>(x, filt, out);
}